// Round 1
// 220.088 us; speedup vs baseline: 1.0060x; 1.0060x over previous
//
#include <hip/hip_runtime.h>

#define BINS 25
#define H 512
#define W 512
#define NPLANES 96   // B*C = 32*3
#define NSH 32       // sub-histograms per block
#define BPP 8        // blocks per plane (was 4): 1536 blocks = 6/CU = 24 waves/CU

// Block = 256 threads = 4 waves; block b covers plane z = b>>3, y-strips
// 4*(b&7) .. 4*(b&7)+3 (one 8-output-row strip per wave).
// Thread: x-lane i = tid&63 owns output cols 4i..4i+3; walks 8 output rows.
// No barriers in the walk: 7-row register window of h-blurred float4s.
__global__ __launch_bounds__(256) void blur_hist(
        const float* __restrict__ x, const float* __restrict__ y,
        unsigned int* __restrict__ partial) {
    const int b = blockIdx.x;
    const int z = b >> 3;
    const float* src = (z < NPLANES) ? x + (size_t)z * H * W
                                     : y + (size_t)(z - NPLANES) * H * W;

    __shared__ unsigned int sh[NSH * BINS];   // 3.2 KB
    const int tid = threadIdx.x;
    if (tid < (NSH * BINS / 4))
        *(float4*)((float*)sh + 4 * tid) = make_float4(0.f, 0.f, 0.f, 0.f);
    __syncthreads();

    const int i = tid & 63;                   // x-lane
    const int s = (b & 7) * 4 + (tid >> 6);   // y-strip 0..31 (wave-uniform)
    const int c0 = 8 * i - 4;                 // col of quad0
    const int o0 = (i == 0)  ? 0   : c0;      // clamped quad0 col
    const int o3 = (i == 63) ? 508 : c0 + 12; // clamped quad3 col
    const float m0 = (i == 0)  ? 0.f : 1.f;   // zero-mask for left halo
    const float m3 = (i == 63) ? 0.f : 1.f;   // zero-mask for right halo

    const float w0 = 1.f/64.f, w1 = 6.f/64.f, w2 = 15.f/64.f, w3 = 20.f/64.f;

    // load input row gy, horizontal 7-tap blur (stride 2) for 4 output cols
    auto load_row = [&](int gy) -> float4 {
        float4 h = make_float4(0.f, 0.f, 0.f, 0.f);
        if ((unsigned)gy < (unsigned)H) {     // wave-uniform branch
            const float* rp = src + (size_t)gy * W;
            float4 Q0 = *(const float4*)(rp + o0);
            float4 Q1 = *(const float4*)(rp + c0 + 4);
            float4 Q2 = *(const float4*)(rp + c0 + 8);
            float4 Q3 = *(const float4*)(rp + o3);
            float r1 = Q0.y * m0, r2 = Q0.z * m0, r3 = Q0.w * m0;
            float r4 = Q1.x, r5 = Q1.y, r6 = Q1.z, r7 = Q1.w;
            float r8 = Q2.x, r9 = Q2.y, r10 = Q2.z, r11 = Q2.w;
            float r12 = Q3.x * m3, r13 = Q3.y * m3;
            h.x = w0*(r1 + r7)  + w1*(r2 + r6)  + w2*(r3 + r5)  + w3*r4;
            h.y = w0*(r3 + r9)  + w1*(r4 + r8)  + w2*(r5 + r7)  + w3*r6;
            h.z = w0*(r5 + r11) + w1*(r6 + r10) + w2*(r7 + r9)  + w3*r8;
            h.w = w0*(r7 + r13) + w1*(r8 + r12) + w2*(r9 + r11) + w3*r10;
        }
        return h;
    };

    unsigned int* wh = sh + (tid & (NSH - 1)) * BINS;
    auto binit = [&](float v) {
        int bb = min((int)(v * 25.f), BINS - 1);   // v in [0,1] by construction
        atomicAdd(&wh[bb], 1u);
    };
    auto vout = [&](const float4& h0, const float4& h1, const float4& h2,
                    const float4& h3, const float4& h4, const float4& h5,
                    const float4& h6) {
        binit(w0*(h0.x+h6.x) + w1*(h1.x+h5.x) + w2*(h2.x+h4.x) + w3*h3.x);
        binit(w0*(h0.y+h6.y) + w1*(h1.y+h5.y) + w2*(h2.y+h4.y) + w3*h3.y);
        binit(w0*(h0.z+h6.z) + w1*(h1.z+h5.z) + w2*(h2.z+h4.z) + w3*h3.z);
        binit(w0*(h0.w+h6.w) + w1*(h1.w+h5.w) + w2*(h2.w+h4.w) + w3*h3.w);
    };

    // ---- register-window walk: rows 2oy-3..2oy+3 live as h0..h6 ----
    const int gy0 = 16 * s - 3;
    float4 h0 = load_row(gy0 + 0), h1 = load_row(gy0 + 1), h2 = load_row(gy0 + 2),
           h3 = load_row(gy0 + 3), h4 = load_row(gy0 + 4), h5 = load_row(gy0 + 5),
           h6 = load_row(gy0 + 6);
    #pragma unroll
    for (int j = 0; j < 7; j++) {
        float4 hA = load_row(gy0 + 7 + 2 * j);   // next-iter rows: loads in
        float4 hB = load_row(gy0 + 8 + 2 * j);   // flight over compute below
        vout(h0, h1, h2, h3, h4, h5, h6);
        h0 = h2; h1 = h3; h2 = h4; h3 = h5; h4 = h6; h5 = hA; h6 = hB;
    }
    vout(h0, h1, h2, h3, h4, h5, h6);
    __syncthreads();

    // ---- one histogram writeout per block ----
    if (tid < BINS) {
        unsigned int acc = 0;
        #pragma unroll
        for (int g = 0; g < NSH; g++) acc += sh[g * BINS + tid];
        partial[b * BINS + tid] = acc;
    }
}

// 96 blocks x 64 threads: plane p gathers its 8 block-partials for x and y,
// cosine sim, atomic mean into out[0].
__global__ __launch_bounds__(64) void reduce_cos(
        const unsigned int* __restrict__ partial, float* __restrict__ out) {
    __shared__ float sa[BINS], sb[BINS];
    const int p = blockIdx.x;
    const int t = threadIdx.x;
    if (t < BINS) {
        unsigned int a = 0, bb = 0;
        #pragma unroll
        for (int j = 0; j < BPP; j++) {
            a  += partial[((size_t)p * BPP + j) * BINS + t];
            bb += partial[((size_t)(NPLANES + p) * BPP + j) * BINS + t];
        }
        sa[t] = (float)a;
        sb[t] = (float)bb;
    }
    __syncthreads();
    if (t == 0) {
        const float inv_hw = 1.0f / (float)(H * W);
        float dot = 0.f, nx = 0.f, ny = 0.f;
        for (int k = 0; k < BINS; k++) {
            float a = sa[k] * inv_hw;
            float c = sb[k] * inv_hw;
            dot += a * c;
            nx  += a * a;
            ny  += c * c;
        }
        nx = fmaxf(sqrtf(nx), 1e-6f);
        ny = fmaxf(sqrtf(ny), 1e-6f);
        atomicAdd(out, (dot / (nx * ny)) * (1.0f / (float)NPLANES));
    }
}

extern "C" void kernel_launch(void* const* d_in, const int* in_sizes, int n_in,
                              void* d_out, int out_size, void* d_ws, size_t ws_size,
                              hipStream_t stream) {
    const float* x = (const float*)d_in[0];
    const float* y = (const float*)d_in[1];
    float* out = (float*)d_out;

    unsigned int* partial = (unsigned int*)d_ws;   // [1536][25] u32 = 153.6 KB

    hipMemsetAsync(out, 0, sizeof(float), stream);

    blur_hist<<<2 * NPLANES * BPP, 256, 0, stream>>>(x, y, partial);
    reduce_cos<<<NPLANES, 64, 0, stream>>>(partial, out);
}